// Round 6
// baseline (230.252 us; speedup 1.0000x reference)
//
#include <hip/hip_runtime.h>
#include <math.h>

#define B_  4
#define T_  16
#define C_  64
#define CQ_ 8
#define HW_ 9216          // 96*96
#define NCHUNK_ 288       // HW_/32

typedef __attribute__((ext_vector_type(8))) short  s16x8;  // 8 bf16 = 4 VGPR
typedef __attribute__((ext_vector_type(4))) short  s16x4;
typedef __attribute__((ext_vector_type(4))) float  f32x4;

static __device__ __forceinline__ short f2bf(float f) {
  union { float f; unsigned u; } v; v.f = f;
  return (short)((v.u + 0x7FFFu + ((v.u >> 16) & 1u)) >> 16);  // RNE
}

// ---------------------------------------------------------------------------
// k_prep: transpose conv weights so each ci's row (8 cq x 3 taps = 24 floats)
// is contiguous (stride 32) -> enables scalar (s_load) fetches in k_energy.
// ---------------------------------------------------------------------------
__global__ __launch_bounds__(256)
void k_prep(const float* __restrict__ wq, const float* __restrict__ wk,
            float* __restrict__ WT) {
  for (int j = threadIdx.x; j < CQ_ * C_ * 3; j += 256) {
    int ci = j / 24, r = j % 24;      // r = cqi*3 + d
    int cqi = r / 3, d = r % 3;
    WT[ci * 32 + r]        = wq[(cqi * C_ + ci) * 3 + d];
    WT[2048 + ci * 32 + r] = wk[(cqi * C_ + ci) * 3 + d];
  }
}

// ---------------------------------------------------------------------------
// k_energy: partial energies. grid (288, 4), block 512 = (t=16 x g=32).
// (unchanged — next round's target)
// ---------------------------------------------------------------------------
__global__ __launch_bounds__(512, 4)
void k_energy(const float* __restrict__ x, const float* __restrict__ WT,
              const float* __restrict__ bq, const float* __restrict__ bk,
              float* __restrict__ partE) {
  __shared__ __attribute__((aligned(16))) float QK[2 * 32 * 196];
  __shared__ float Etmp[256];

  const int b   = blockIdx.y;
  const int hw0 = blockIdx.x * 32;
  const int tid = threadIdx.x;
  const int t = tid >> 5;   // 0..15
  const int g = tid & 31;   // 0..31
  const float* xb  = x + (size_t)(b * T_ * C_) * HW_ + hw0 + g;
  const float* wqt = WT;           // [ci*32 + cqi*3 + d]
  const float* wkt = WT + 2048;

  float qa[CQ_], ka[CQ_];
#pragma unroll
  for (int j = 0; j < CQ_; ++j) { qa[j] = 0.f; ka[j] = 0.f; }

#pragma unroll 2
  for (int ci = 0; ci < C_; ++ci) {
    float xm = 0.f, xp = 0.f;
    if (t > 0)      xm = xb[(size_t)((t - 1) * C_ + ci) * HW_];
    float x0 =           xb[(size_t)(t * C_ + ci) * HW_];
    if (t < T_ - 1) xp = xb[(size_t)((t + 1) * C_ + ci) * HW_];
    const float* wq_r = &wqt[ci * 32];
    const float* wk_r = &wkt[ci * 32];
#pragma unroll
    for (int j = 0; j < CQ_; ++j) {
      qa[j] += wq_r[j * 3 + 0] * xm + wq_r[j * 3 + 1] * x0 + wq_r[j * 3 + 2] * xp;
      ka[j] += wk_r[j * 3 + 0] * xm + wk_r[j * 3 + 1] * x0 + wk_r[j * 3 + 2] * xp;
    }
  }
#pragma unroll
  for (int j = 0; j < CQ_; ++j) { qa[j] += bq[j]; ka[j] += bk[j]; }

  float* Qs = &QK[0];
  float* Ks = &QK[32 * 196];
#pragma unroll
  for (int j = 0; j < CQ_; ++j) {
    Qs[g * 196 + t * 12 + j] = qa[j];
    Ks[g * 196 + t * 12 + j] = ka[j];
  }
  __syncthreads();

  const int h  = tid >> 8;
  const int tt = (tid >> 4) & 15;
  const int ss = tid & 15;
  float e = 0.f;
  for (int gg = h * 16; gg < h * 16 + 16; ++gg) {
    const float4 q0 = *(const float4*)&Qs[gg * 196 + tt * 12];
    const float4 q1 = *(const float4*)&Qs[gg * 196 + tt * 12 + 4];
    const float4 k0 = *(const float4*)&Ks[gg * 196 + ss * 12];
    const float4 k1 = *(const float4*)&Ks[gg * 196 + ss * 12 + 4];
    e += q0.x * k0.x + q0.y * k0.y + q0.z * k0.z + q0.w * k0.w
       + q1.x * k1.x + q1.y * k1.y + q1.z * k1.z + q1.w * k1.w;
  }
  if (h == 1) Etmp[tt * 16 + ss] = e;
  __syncthreads();
  if (h == 0) {
    e += Etmp[tt * 16 + ss];
    partE[((size_t)(b * NCHUNK_ + blockIdx.x)) * 256 + tt * 16 + ss] = e;
  }
}

// ---------------------------------------------------------------------------
// k_softmax: reduce 288 partials and softmax over s. grid 4, block 256.
// ---------------------------------------------------------------------------
__global__ __launch_bounds__(256)
void k_softmax(const float* __restrict__ partE, float* __restrict__ heat) {
  const int b = blockIdx.x;
  const int tid = threadIdx.x;
  float e = 0.f;
  for (int ch = 0; ch < NCHUNK_; ++ch)
    e += partE[((size_t)(b * NCHUNK_ + ch)) * 256 + tid];
  float mx = e;
#pragma unroll
  for (int m = 1; m < 16; m <<= 1) mx = fmaxf(mx, __shfl_xor(mx, m, 64));
  float ex = expf(e - mx);
  float sm = ex;
#pragma unroll
  for (int m = 1; m < 16; m <<= 1) sm += __shfl_xor(sm, m, 64);
  heat[b * 256 + tid] = ex / sm;
}

// ---------------------------------------------------------------------------
// k_mix (MFMA): per block (b, 16-g tile): out = gamma*(Wv @ (heat @ X)) + bias
// + residual.  Two chained mfma_f32_16x16x32_bf16 GEMMs (round-5 structure).
// Round-6 changes:
//  (a) residual loads HOISTED to right after staging — same cache lines just
//      fetched -> L2/L1-hot (round-5 read them at epilogue time: L2 evicted,
//      FETCH was 2x = 294 MB). Held as bf16 pairs in 32 VGPRs.
//  (b) GEMM1 B-loads de-diverged: lanes lq>=2 alias lq&1's rows (their A
//      operand is 0, product is 0) — no exec-mask churn, no NaN risk.
// ---------------------------------------------------------------------------
__global__ __launch_bounds__(256, 3)
void k_mix(const float* __restrict__ x, const float* __restrict__ heat,
           const float* __restrict__ wv, const float* __restrict__ bv,
           const float* __restrict__ gam, float* __restrict__ out) {
  __shared__ __attribute__((aligned(16))) short sm[24576];  // 48 KB union

  const int b    = blockIdx.y;
  const int hw0  = blockIdx.x * 16;
  const int tid  = threadIdx.x;
  const int lane = tid & 63;
  const int w    = tid >> 6;      // wave 0..3
  const int l15  = lane & 15;
  const int lq   = lane >> 4;     // quarter 0..3

  union U8 { s16x8 v; int i[4]; };
  const f32x4 fz = {0.f, 0.f, 0.f, 0.f};

  // ---- stage x tile -> bf16 xs -------------------------------------------
  {
    const int ci = tid >> 2, q = tid & 3;
    const int sw = 2 * (ci & 7);
    const float* xp = x + ((size_t)b * T_ * C_ + ci) * HW_ + hw0 + q * 4;
    short* r0 = &sm[(ci * 16 + q * 4 + 0) * 24];
    short* r1 = r0 + 24; short* r2 = r0 + 48; short* r3 = r0 + 72;
#pragma unroll
    for (int s = 0; s < T_; ++s) {
      float4 v = *(const float4*)(xp + (size_t)s * C_ * HW_);
      const int sp = s ^ sw;
      r0[sp] = f2bf(v.x); r1[sp] = f2bf(v.y);
      r2[sp] = f2bf(v.z); r3[sp] = f2bf(v.w);
    }
  }

  // ---- hoisted residual loads (L2-hot: staged lines just fetched) --------
  // res[(ct*4+ntq)*2 + (r>>1)]: bf16 pair for c = ct*16+lq*4+{r, r+1},
  // t = w*4+ntq, g = l15.  r&1==0 -> low half, r&1==1 -> high half.
  unsigned res[32];
  {
    const float* resb = x + (size_t)(b * T_ * C_) * HW_ + hw0 + l15;
#pragma unroll
    for (int ct = 0; ct < 4; ++ct)
#pragma unroll
      for (int ntq = 0; ntq < 4; ++ntq) {
        const float* p = resb +
            ((size_t)((w * 4 + ntq) * C_ + ct * 16 + lq * 4)) * HW_;
        float v0 = p[0];
        float v1 = p[HW_];
        float v2 = p[2 * (size_t)HW_];
        float v3 = p[3 * (size_t)HW_];
        res[(ct * 4 + ntq) * 2 + 0] =
            (unsigned)(unsigned short)f2bf(v0) |
            ((unsigned)(unsigned short)f2bf(v1) << 16);
        res[(ct * 4 + ntq) * 2 + 1] =
            (unsigned)(unsigned short)f2bf(v2) |
            ((unsigned)(unsigned short)f2bf(v3) << 16);
      }
  }

  // ---- A1 fragment: heat[t][s], K=16 zero-padded to 32 -------------------
  U8 ha; ha.i[0] = ha.i[1] = ha.i[2] = ha.i[3] = 0;
  if (lane < 32) {
    const float* hp = heat + b * 256 + l15 * 16 + lq * 8;
    float4 h0 = *(const float4*)hp;
    float4 h1 = *(const float4*)(hp + 4);
    ha.v[0] = f2bf(h0.x); ha.v[1] = f2bf(h0.y);
    ha.v[2] = f2bf(h0.z); ha.v[3] = f2bf(h0.w);
    ha.v[4] = f2bf(h1.x); ha.v[5] = f2bf(h1.y);
    ha.v[6] = f2bf(h1.z); ha.v[7] = f2bf(h1.w);
  }
  __syncthreads();

  // ---- GEMM1: 16 MFMAs, ci-tile = w*16+i ----------------------------------
  // c1[i]: lane holds xh[t=(lq*4+reg)][ci=w*16+i][g=l15]
  const int lq2 = lq & 1;   // lanes lq>=2 alias lq-2's B rows (A there is 0)
  f32x4 c1[16];
#pragma unroll
  for (int i = 0; i < 16; ++i) {
    const int ci = w * 16 + i;
    const int rowb = (ci * 16 + l15) * 24;
    const int sw = 2 * (ci & 7);
    const int s0 = lq2 * 8;
    U8 bx;
#pragma unroll
    for (int m = 0; m < 4; ++m)
      bx.i[m] = *(const int*)&sm[rowb + ((s0 + 2 * m) ^ sw)];
    c1[i] = __builtin_amdgcn_mfma_f32_16x16x32_bf16(ha.v, bx.v, fz, 0, 0, 0);
  }
  __syncthreads();   // all xs reads done; sm becomes xh

  // ---- write xh -> LDS [n=t*16+g][ci] (stride 72), bf16, b64 packs -------
#pragma unroll
  for (int r = 0; r < 4; ++r) {
    const int t = lq * 4 + r;
    short* dst = &sm[(t * 16 + l15) * 72 + w * 16];
#pragma unroll
    for (int q = 0; q < 4; ++q) {
      s16x4 pk;
      pk[0] = f2bf(c1[q * 4 + 0][r]); pk[1] = f2bf(c1[q * 4 + 1][r]);
      pk[2] = f2bf(c1[q * 4 + 2][r]); pk[3] = f2bf(c1[q * 4 + 3][r]);
      *(s16x4*)(dst + q * 4) = pk;
    }
  }

  // ---- A2 fragments: Wv (4 c-tiles x 2 k-steps) + bias + gamma -----------
  U8 a2[8];
#pragma unroll
  for (int ct = 0; ct < 4; ++ct)
#pragma unroll
    for (int ks = 0; ks < 2; ++ks) {
      const float* wp = wv + (ct * 16 + l15) * C_ + ks * 32 + lq * 8;
      float4 w0 = *(const float4*)wp;
      float4 w1 = *(const float4*)(wp + 4);
      U8 f;
      f.v[0] = f2bf(w0.x); f.v[1] = f2bf(w0.y);
      f.v[2] = f2bf(w0.z); f.v[3] = f2bf(w0.w);
      f.v[4] = f2bf(w1.x); f.v[5] = f2bf(w1.y);
      f.v[6] = f2bf(w1.z); f.v[7] = f2bf(w1.w);
      a2[ct * 2 + ks] = f;
    }
  f32x4 bvr[4];
#pragma unroll
  for (int ct = 0; ct < 4; ++ct)
    bvr[ct] = *(const f32x4*)(bv + ct * 16 + lq * 4);
  const float gamma = gam[0];
  __syncthreads();   // xh visible

  // ---- GEMM2 + epilogue: this wave owns t = w*4 .. w*4+3 ------------------
#pragma unroll
  for (int ntq = 0; ntq < 4; ++ntq) {
    const int t = w * 4 + ntq;
    const short* xr0 = &sm[(t * 16 + l15) * 72];
    s16x8 b0 = *(const s16x8*)(xr0 + lq * 8);        // k = ci   0..31 slice
    s16x8 b1 = *(const s16x8*)(xr0 + 32 + lq * 8);   // k = ci  32..63 slice
    float* op = out + ((size_t)(b * T_ + t) * C_) * HW_ + hw0 + l15;
#pragma unroll
    for (int ct = 0; ct < 4; ++ct) {
      f32x4 acc = __builtin_amdgcn_mfma_f32_16x16x32_bf16(a2[ct * 2 + 0].v, b0, fz, 0, 0, 0);
      acc = __builtin_amdgcn_mfma_f32_16x16x32_bf16(a2[ct * 2 + 1].v, b1, acc, 0, 0, 0);
      const int cb = ct * 16 + lq * 4;
      const unsigned r01 = res[(ct * 4 + ntq) * 2 + 0];
      const unsigned r23 = res[(ct * 4 + ntq) * 2 + 1];
      union { unsigned u; float f; } z0, z1, z2, z3;
      z0.u = r01 << 16;          // r = 0
      z1.u = r01 & 0xffff0000u;  // r = 1
      z2.u = r23 << 16;          // r = 2
      z3.u = r23 & 0xffff0000u;  // r = 3
      op[(size_t)(cb + 0) * HW_] = gamma * (acc[0] + bvr[ct][0]) + z0.f;
      op[(size_t)(cb + 1) * HW_] = gamma * (acc[1] + bvr[ct][1]) + z1.f;
      op[(size_t)(cb + 2) * HW_] = gamma * (acc[2] + bvr[ct][2]) + z2.f;
      op[(size_t)(cb + 3) * HW_] = gamma * (acc[3] + bvr[ct][3]) + z3.f;
    }
  }
}

// ---------------------------------------------------------------------------
extern "C" void kernel_launch(void* const* d_in, const int* in_sizes, int n_in,
                              void* d_out, int out_size, void* d_ws, size_t ws_size,
                              hipStream_t stream) {
  const float* x   = (const float*)d_in[0];
  const float* wq  = (const float*)d_in[1];
  const float* bq  = (const float*)d_in[2];
  const float* wk  = (const float*)d_in[3];
  const float* bk  = (const float*)d_in[4];
  const float* wv  = (const float*)d_in[5];
  const float* bv  = (const float*)d_in[6];
  const float* gam = (const float*)d_in[7];
  float* out = (float*)d_out;

  float* WT    = (float*)d_ws;                        // 2*64*32 = 4096 floats
  float* partE = WT + 4096;                           // 4*288*256 floats
  float* heat  = partE + (size_t)B_ * NCHUNK_ * 256;  // 4*256 floats

  k_prep   <<<1, 256, 0, stream>>>(wq, wk, WT);
  k_energy <<<dim3(NCHUNK_, B_), 512, 0, stream>>>(x, WT, bq, bk, partE);
  k_softmax<<<dim3(B_),          256, 0, stream>>>(partE, heat);
  k_mix    <<<dim3(HW_ / 16, B_), 256, 0, stream>>>(x, heat, wv, bv, gam, out);
}

// Round 7
// 226.511 us; speedup vs baseline: 1.0165x; 1.0165x over previous
//
#include <hip/hip_runtime.h>
#include <math.h>

#define B_  4
#define T_  16
#define C_  64
#define CQ_ 8
#define HW_ 9216          // 96*96
#define NCHUNK_ 288       // HW_/32

typedef __attribute__((ext_vector_type(8))) short  s16x8;  // 8 bf16 = 4 VGPR
typedef __attribute__((ext_vector_type(4))) short  s16x4;
typedef __attribute__((ext_vector_type(4))) float  f32x4;

static __device__ __forceinline__ short f2bf(float f) {
  union { float f; unsigned u; } v; v.f = f;
  return (short)((v.u + 0x7FFFu + ((v.u >> 16) & 1u)) >> 16);  // RNE
}

// ---------------------------------------------------------------------------
// k_prep: transpose conv weights so each ci's row (8 cq x 3 taps = 24 floats)
// is contiguous (stride 32) -> enables scalar (s_load) fetches in k_energy.
// ---------------------------------------------------------------------------
__global__ __launch_bounds__(256)
void k_prep(const float* __restrict__ wq, const float* __restrict__ wk,
            float* __restrict__ WT) {
  for (int j = threadIdx.x; j < CQ_ * C_ * 3; j += 256) {
    int ci = j / 24, r = j % 24;      // r = cqi*3 + d
    int cqi = r / 3, d = r % 3;
    WT[ci * 32 + r]        = wq[(cqi * C_ + ci) * 3 + d];
    WT[2048 + ci * 32 + r] = wk[(cqi * C_ + ci) * 3 + d];
  }
}

// ---------------------------------------------------------------------------
// k_energy: partial energies. grid (288, 4), block 512 = (t=16 x g=32).
// (unchanged — next round's target)
// ---------------------------------------------------------------------------
__global__ __launch_bounds__(512, 4)
void k_energy(const float* __restrict__ x, const float* __restrict__ WT,
              const float* __restrict__ bq, const float* __restrict__ bk,
              float* __restrict__ partE) {
  __shared__ __attribute__((aligned(16))) float QK[2 * 32 * 196];
  __shared__ float Etmp[256];

  const int b   = blockIdx.y;
  const int hw0 = blockIdx.x * 32;
  const int tid = threadIdx.x;
  const int t = tid >> 5;   // 0..15
  const int g = tid & 31;   // 0..31
  const float* xb  = x + (size_t)(b * T_ * C_) * HW_ + hw0 + g;
  const float* wqt = WT;           // [ci*32 + cqi*3 + d]
  const float* wkt = WT + 2048;

  float qa[CQ_], ka[CQ_];
#pragma unroll
  for (int j = 0; j < CQ_; ++j) { qa[j] = 0.f; ka[j] = 0.f; }

#pragma unroll 2
  for (int ci = 0; ci < C_; ++ci) {
    float xm = 0.f, xp = 0.f;
    if (t > 0)      xm = xb[(size_t)((t - 1) * C_ + ci) * HW_];
    float x0 =           xb[(size_t)(t * C_ + ci) * HW_];
    if (t < T_ - 1) xp = xb[(size_t)((t + 1) * C_ + ci) * HW_];
    const float* wq_r = &wqt[ci * 32];
    const float* wk_r = &wkt[ci * 32];
#pragma unroll
    for (int j = 0; j < CQ_; ++j) {
      qa[j] += wq_r[j * 3 + 0] * xm + wq_r[j * 3 + 1] * x0 + wq_r[j * 3 + 2] * xp;
      ka[j] += wk_r[j * 3 + 0] * xm + wk_r[j * 3 + 1] * x0 + wk_r[j * 3 + 2] * xp;
    }
  }
#pragma unroll
  for (int j = 0; j < CQ_; ++j) { qa[j] += bq[j]; ka[j] += bk[j]; }

  float* Qs = &QK[0];
  float* Ks = &QK[32 * 196];
#pragma unroll
  for (int j = 0; j < CQ_; ++j) {
    Qs[g * 196 + t * 12 + j] = qa[j];
    Ks[g * 196 + t * 12 + j] = ka[j];
  }
  __syncthreads();

  const int h  = tid >> 8;
  const int tt = (tid >> 4) & 15;
  const int ss = tid & 15;
  float e = 0.f;
  for (int gg = h * 16; gg < h * 16 + 16; ++gg) {
    const float4 q0 = *(const float4*)&Qs[gg * 196 + tt * 12];
    const float4 q1 = *(const float4*)&Qs[gg * 196 + tt * 12 + 4];
    const float4 k0 = *(const float4*)&Ks[gg * 196 + ss * 12];
    const float4 k1 = *(const float4*)&Ks[gg * 196 + ss * 12 + 4];
    e += q0.x * k0.x + q0.y * k0.y + q0.z * k0.z + q0.w * k0.w
       + q1.x * k1.x + q1.y * k1.y + q1.z * k1.z + q1.w * k1.w;
  }
  if (h == 1) Etmp[tt * 16 + ss] = e;
  __syncthreads();
  if (h == 0) {
    e += Etmp[tt * 16 + ss];
    partE[((size_t)(b * NCHUNK_ + blockIdx.x)) * 256 + tt * 16 + ss] = e;
  }
}

// ---------------------------------------------------------------------------
// k_softmax: reduce 288 partials and softmax over s. grid 4, block 256.
// ---------------------------------------------------------------------------
__global__ __launch_bounds__(256)
void k_softmax(const float* __restrict__ partE, float* __restrict__ heat) {
  const int b = blockIdx.x;
  const int tid = threadIdx.x;
  float e = 0.f;
  for (int ch = 0; ch < NCHUNK_; ++ch)
    e += partE[((size_t)(b * NCHUNK_ + ch)) * 256 + tid];
  float mx = e;
#pragma unroll
  for (int m = 1; m < 16; m <<= 1) mx = fmaxf(mx, __shfl_xor(mx, m, 64));
  float ex = expf(e - mx);
  float sm = ex;
#pragma unroll
  for (int m = 1; m < 16; m <<= 1) sm += __shfl_xor(sm, m, 64);
  heat[b * 256 + tid] = ex / sm;
}

// ---------------------------------------------------------------------------
// k_mix (MFMA): out = gamma*(Wv @ (heat @ X)) + bias + residual.
// Round-7 changes vs round-6:
//  (a) residual comes from LDS (xs IS x in bf16) — read after GEMM1, before
//      xs is overwritten by xh. Rounds 5/6 re-read it from HBM (+~120 MB
//      FETCH: per-XCD L2 cycles in ~3 µs, lines already evicted).
//      For fixed c, the 4 t-values sit in one aligned 4-short group under
//      the XOR swizzle: positions (w*4+j)^sw, j=0..3 = base+{0..3} with
//      base=((w*4)^sw)&~3, pair-swapped iff c&1 -> 2 b32 reads + cndmask.
//  (b) xs stride 24->20 shorts: LDS 48->40 KB -> 4 blocks/CU (16 waves/CU,
//      was 12) to attack latency-boundness. Banks: staging writes hit
//      (lane&3)*8 + (s>>1)^(q4&7) = 32 distinct -> conflict-free; GEMM1
//      reads l15*10 mod 32 = 16 distinct -> free.
// ---------------------------------------------------------------------------
__global__ __launch_bounds__(256, 4)
void k_mix(const float* __restrict__ x, const float* __restrict__ heat,
           const float* __restrict__ wv, const float* __restrict__ bv,
           const float* __restrict__ gam, float* __restrict__ out) {
  __shared__ __attribute__((aligned(16))) short sm[20480];  // 40 KB union

  const int b    = blockIdx.y;
  const int hw0  = blockIdx.x * 16;
  const int tid  = threadIdx.x;
  const int lane = tid & 63;
  const int w    = tid >> 6;      // wave 0..3
  const int l15  = lane & 15;
  const int lq   = lane >> 4;     // quarter 0..3

  union U8 { s16x8 v; int i[4]; };
  const f32x4 fz = {0.f, 0.f, 0.f, 0.f};

  // ---- stage x tile -> bf16 xs: row (ci*16+g), stride 20, s XOR-swizzled --
  {
    const int ci = tid >> 2, q = tid & 3;
    const int sw = 2 * (ci & 7);
    const float* xp = x + ((size_t)b * T_ * C_ + ci) * HW_ + hw0 + q * 4;
    short* r0 = &sm[(ci * 16 + q * 4 + 0) * 20];
    short* r1 = r0 + 20; short* r2 = r0 + 40; short* r3 = r0 + 60;
#pragma unroll
    for (int s = 0; s < T_; ++s) {
      float4 v = *(const float4*)(xp + (size_t)s * C_ * HW_);
      const int sp = s ^ sw;
      r0[sp] = f2bf(v.x); r1[sp] = f2bf(v.y);
      r2[sp] = f2bf(v.z); r3[sp] = f2bf(v.w);
    }
  }

  // ---- A1 fragment: heat[t][s], K=16 zero-padded to 32 -------------------
  U8 ha; ha.i[0] = ha.i[1] = ha.i[2] = ha.i[3] = 0;
  if (lane < 32) {
    const float* hp = heat + b * 256 + l15 * 16 + lq * 8;
    float4 h0 = *(const float4*)hp;
    float4 h1 = *(const float4*)(hp + 4);
    ha.v[0] = f2bf(h0.x); ha.v[1] = f2bf(h0.y);
    ha.v[2] = f2bf(h0.z); ha.v[3] = f2bf(h0.w);
    ha.v[4] = f2bf(h1.x); ha.v[5] = f2bf(h1.y);
    ha.v[6] = f2bf(h1.z); ha.v[7] = f2bf(h1.w);
  }
  __syncthreads();

  // ---- GEMM1: 16 MFMAs, ci = w*16+i ---------------------------------------
  // c1[i]: lane holds xh[t=(lq*4+reg)][ci=w*16+i][g=l15]
  const int lq2 = lq & 1;   // lanes lq>=2 alias lq-2's B rows (A there is 0)
  f32x4 c1[16];
#pragma unroll
  for (int i = 0; i < 16; ++i) {
    const int ci = w * 16 + i;
    const int rowb = (ci * 16 + l15) * 20;
    const int sw = 2 * (ci & 7);
    const int s0 = lq2 * 8;
    U8 bx;
#pragma unroll
    for (int m = 0; m < 4; ++m)
      bx.i[m] = *(const int*)&sm[rowb + ((s0 + 2 * m) ^ sw)];
    c1[i] = __builtin_amdgcn_mfma_f32_16x16x32_bf16(ha.v, bx.v, fz, 0, 0, 0);
  }

  // ---- residual from LDS (xs still valid): rc[(ct*4+r)*2+half] holds the
  //      bf16 pair (t = w*4+2*half, w*4+2*half+1) for c = ct*16+lq*4+r,
  //      g = l15.
  unsigned rc[32];
#pragma unroll
  for (int ct = 0; ct < 4; ++ct)
#pragma unroll
    for (int r = 0; r < 4; ++r) {
      const int c  = ct * 16 + lq * 4 + r;
      const int sw = 2 * (c & 7);
      const int base = (c * 16 + l15) * 20 + (((w * 4) ^ sw) & ~3);
      unsigned L0 = *(const unsigned*)&sm[base];
      unsigned L1 = *(const unsigned*)&sm[base + 2];
      const bool swp = (c & 1);          // sw&2 -> pair order swapped
      rc[(ct * 4 + r) * 2 + 0] = swp ? L1 : L0;
      rc[(ct * 4 + r) * 2 + 1] = swp ? L0 : L1;
    }
  __syncthreads();   // all xs reads done; sm becomes xh

  // ---- write xh -> LDS [n=t*16+g][ci] (stride 72), bf16, b64 packs -------
#pragma unroll
  for (int r = 0; r < 4; ++r) {
    const int t = lq * 4 + r;
    short* dst = &sm[(t * 16 + l15) * 72 + w * 16];
#pragma unroll
    for (int q = 0; q < 4; ++q) {
      s16x4 pk;
      pk[0] = f2bf(c1[q * 4 + 0][r]); pk[1] = f2bf(c1[q * 4 + 1][r]);
      pk[2] = f2bf(c1[q * 4 + 2][r]); pk[3] = f2bf(c1[q * 4 + 3][r]);
      *(s16x4*)(dst + q * 4) = pk;
    }
  }

  // ---- A2 fragments: Wv (4 c-tiles x 2 k-steps) + bias + gamma -----------
  U8 a2[8];
#pragma unroll
  for (int ct = 0; ct < 4; ++ct)
#pragma unroll
    for (int ks = 0; ks < 2; ++ks) {
      const float* wp = wv + (ct * 16 + l15) * C_ + ks * 32 + lq * 8;
      float4 w0 = *(const float4*)wp;
      float4 w1 = *(const float4*)(wp + 4);
      U8 f;
      f.v[0] = f2bf(w0.x); f.v[1] = f2bf(w0.y);
      f.v[2] = f2bf(w0.z); f.v[3] = f2bf(w0.w);
      f.v[4] = f2bf(w1.x); f.v[5] = f2bf(w1.y);
      f.v[6] = f2bf(w1.z); f.v[7] = f2bf(w1.w);
      a2[ct * 2 + ks] = f;
    }
  f32x4 bvr[4];
#pragma unroll
  for (int ct = 0; ct < 4; ++ct)
    bvr[ct] = *(const f32x4*)(bv + ct * 16 + lq * 4);
  const float gamma = gam[0];
  __syncthreads();   // xh visible

  // ---- GEMM2 + epilogue: this wave owns t = w*4 .. w*4+3 ------------------
#pragma unroll
  for (int ntq = 0; ntq < 4; ++ntq) {
    const int t = w * 4 + ntq;
    const short* xr0 = &sm[(t * 16 + l15) * 72];
    s16x8 b0 = *(const s16x8*)(xr0 + lq * 8);        // k = ci   0..31 slice
    s16x8 b1 = *(const s16x8*)(xr0 + 32 + lq * 8);   // k = ci  32..63 slice
    float* op = out + ((size_t)(b * T_ + t) * C_) * HW_ + hw0 + l15;
    const int half = ntq >> 1, odd = ntq & 1;
#pragma unroll
    for (int ct = 0; ct < 4; ++ct) {
      f32x4 acc = __builtin_amdgcn_mfma_f32_16x16x32_bf16(a2[ct * 2 + 0].v, b0, fz, 0, 0, 0);
      acc = __builtin_amdgcn_mfma_f32_16x16x32_bf16(a2[ct * 2 + 1].v, b1, acc, 0, 0, 0);
      const int cb = ct * 16 + lq * 4;
#pragma unroll
      for (int r = 0; r < 4; ++r) {
        const unsigned v = rc[(ct * 4 + r) * 2 + half];
        union { unsigned u; float f; } z;
        z.u = odd ? (v & 0xffff0000u) : (v << 16);
        op[(size_t)(cb + r) * HW_] = gamma * (acc[r] + bvr[ct][r]) + z.f;
      }
    }
  }
}

// ---------------------------------------------------------------------------
extern "C" void kernel_launch(void* const* d_in, const int* in_sizes, int n_in,
                              void* d_out, int out_size, void* d_ws, size_t ws_size,
                              hipStream_t stream) {
  const float* x   = (const float*)d_in[0];
  const float* wq  = (const float*)d_in[1];
  const float* bq  = (const float*)d_in[2];
  const float* wk  = (const float*)d_in[3];
  const float* bk  = (const float*)d_in[4];
  const float* wv  = (const float*)d_in[5];
  const float* bv  = (const float*)d_in[6];
  const float* gam = (const float*)d_in[7];
  float* out = (float*)d_out;

  float* WT    = (float*)d_ws;                        // 2*64*32 = 4096 floats
  float* partE = WT + 4096;                           // 4*288*256 floats
  float* heat  = partE + (size_t)B_ * NCHUNK_ * 256;  // 4*256 floats

  k_prep   <<<1, 256, 0, stream>>>(wq, wk, WT);
  k_energy <<<dim3(NCHUNK_, B_), 512, 0, stream>>>(x, WT, bq, bk, partE);
  k_softmax<<<dim3(B_),          256, 0, stream>>>(partE, heat);
  k_mix    <<<dim3(HW_ / 16, B_), 256, 0, stream>>>(x, heat, wv, bv, gam, out);
}

// Round 8
// 175.479 us; speedup vs baseline: 1.3121x; 1.2908x over previous
//
#include <hip/hip_runtime.h>
#include <math.h>

#define B_  4
#define T_  16
#define C_  64
#define CQ_ 8
#define HW_ 9216          // 96*96
#define NCHUNK_ 288       // HW_/32

typedef __attribute__((ext_vector_type(8))) short    s16x8;  // 8 bf16
typedef __attribute__((ext_vector_type(4))) float    f32x4;
typedef __attribute__((ext_vector_type(4))) unsigned u32x4;

static __device__ __forceinline__ short f2bf(float f) {
  union { float f; unsigned u; } v; v.f = f;
  return (short)((v.u + 0x7FFFu + ((v.u >> 16) & 1u)) >> 16);  // RNE
}
static __device__ __forceinline__ unsigned pkbf(float lo, float hi) {
  unsigned r;
  asm("v_cvt_pk_bf16_f32 %0, %1, %2" : "=v"(r) : "v"(lo), "v"(hi));
  return r;   // low16 = bf16(lo), high16 = bf16(hi)
}

// ---------------------------------------------------------------------------
// k_prep: (a) transpose conv weights for k_energy scalar loads;
//         (b) prepack Wv to bf16 in GEMM2 A-fragment order:
//             wvb[((ct*2+ks)*64 + lane)*8 + j] =
//                bf16( wv[(ct*16 + (lane&15))*64 + ks*32 + (lane>>4)*8 + j] )
// ---------------------------------------------------------------------------
__global__ __launch_bounds__(256)
void k_prep(const float* __restrict__ wq, const float* __restrict__ wk,
            const float* __restrict__ wv, float* __restrict__ WT,
            short* __restrict__ wvb) {
  for (int j = threadIdx.x; j < CQ_ * C_ * 3; j += 256) {
    int ci = j / 24, r = j % 24;      // r = cqi*3 + d
    int cqi = r / 3, d = r % 3;
    WT[ci * 32 + r]        = wq[(cqi * C_ + ci) * 3 + d];
    WT[2048 + ci * 32 + r] = wk[(cqi * C_ + ci) * 3 + d];
  }
  for (int idx = threadIdx.x; idx < 4096; idx += 256) {
    int j = idx & 7, lane = (idx >> 3) & 63, fr = idx >> 9;  // fr = ct*2+ks
    int ct = fr >> 1, ks = fr & 1;
    int c  = ct * 16 + (lane & 15);
    int ci = ks * 32 + (lane >> 4) * 8 + j;
    wvb[idx] = f2bf(wv[c * C_ + ci]);
  }
}

// ---------------------------------------------------------------------------
// k_energy: partial energies. grid (288, 4), block 512 = (t=16 x g=32).
// (unchanged — next round's target)
// ---------------------------------------------------------------------------
__global__ __launch_bounds__(512, 4)
void k_energy(const float* __restrict__ x, const float* __restrict__ WT,
              const float* __restrict__ bq, const float* __restrict__ bk,
              float* __restrict__ partE) {
  __shared__ __attribute__((aligned(16))) float QK[2 * 32 * 196];
  __shared__ float Etmp[256];

  const int b   = blockIdx.y;
  const int hw0 = blockIdx.x * 32;
  const int tid = threadIdx.x;
  const int t = tid >> 5;   // 0..15
  const int g = tid & 31;   // 0..31
  const float* xb  = x + (size_t)(b * T_ * C_) * HW_ + hw0 + g;
  const float* wqt = WT;           // [ci*32 + cqi*3 + d]
  const float* wkt = WT + 2048;

  float qa[CQ_], ka[CQ_];
#pragma unroll
  for (int j = 0; j < CQ_; ++j) { qa[j] = 0.f; ka[j] = 0.f; }

#pragma unroll 2
  for (int ci = 0; ci < C_; ++ci) {
    float xm = 0.f, xp = 0.f;
    if (t > 0)      xm = xb[(size_t)((t - 1) * C_ + ci) * HW_];
    float x0 =           xb[(size_t)(t * C_ + ci) * HW_];
    if (t < T_ - 1) xp = xb[(size_t)((t + 1) * C_ + ci) * HW_];
    const float* wq_r = &wqt[ci * 32];
    const float* wk_r = &wkt[ci * 32];
#pragma unroll
    for (int j = 0; j < CQ_; ++j) {
      qa[j] += wq_r[j * 3 + 0] * xm + wq_r[j * 3 + 1] * x0 + wq_r[j * 3 + 2] * xp;
      ka[j] += wk_r[j * 3 + 0] * xm + wk_r[j * 3 + 1] * x0 + wk_r[j * 3 + 2] * xp;
    }
  }
#pragma unroll
  for (int j = 0; j < CQ_; ++j) { qa[j] += bq[j]; ka[j] += bk[j]; }

  float* Qs = &QK[0];
  float* Ks = &QK[32 * 196];
#pragma unroll
  for (int j = 0; j < CQ_; ++j) {
    Qs[g * 196 + t * 12 + j] = qa[j];
    Ks[g * 196 + t * 12 + j] = ka[j];
  }
  __syncthreads();

  const int h  = tid >> 8;
  const int tt = (tid >> 4) & 15;
  const int ss = tid & 15;
  float e = 0.f;
  for (int gg = h * 16; gg < h * 16 + 16; ++gg) {
    const float4 q0 = *(const float4*)&Qs[gg * 196 + tt * 12];
    const float4 q1 = *(const float4*)&Qs[gg * 196 + tt * 12 + 4];
    const float4 k0 = *(const float4*)&Ks[gg * 196 + ss * 12];
    const float4 k1 = *(const float4*)&Ks[gg * 196 + ss * 12 + 4];
    e += q0.x * k0.x + q0.y * k0.y + q0.z * k0.z + q0.w * k0.w
       + q1.x * k1.x + q1.y * k1.y + q1.z * k1.z + q1.w * k1.w;
  }
  if (h == 1) Etmp[tt * 16 + ss] = e;
  __syncthreads();
  if (h == 0) {
    e += Etmp[tt * 16 + ss];
    partE[((size_t)(b * NCHUNK_ + blockIdx.x)) * 256 + tt * 16 + ss] = e;
  }
}

// ---------------------------------------------------------------------------
// k_softmax: reduce 288 partials and softmax over s. grid 4, block 256.
// ---------------------------------------------------------------------------
__global__ __launch_bounds__(256)
void k_softmax(const float* __restrict__ partE, float* __restrict__ heat) {
  const int b = blockIdx.x;
  const int tid = threadIdx.x;
  float e = 0.f;
  for (int ch = 0; ch < NCHUNK_; ++ch)
    e += partE[((size_t)(b * NCHUNK_ + ch)) * 256 + tid];
  float mx = e;
#pragma unroll
  for (int m = 1; m < 16; m <<= 1) mx = fmaxf(mx, __shfl_xor(mx, m, 64));
  float ex = expf(e - mx);
  float sm = ex;
#pragma unroll
  for (int m = 1; m < 16; m <<= 1) sm += __shfl_xor(sm, m, 64);
  heat[b * 256 + tid] = ex / sm;
}

// ---------------------------------------------------------------------------
// k_mix (MFMA, round 8): out = gamma*(Wv @ (heat @ X)) + bias + residual.
// Structure identical to round 7 EXCEPT the latency-chain fixes:
//  (1) barrier #1 removed: wave w stages rows ci=w*16..+15, which is exactly
//      what its GEMM1 reads -> wave-local s_waitcnt lgkmcnt(0) suffices;
//      waves de-phase (one MFMAs while another still loads).
//  (2) staging packs s-PAIRS with v_cvt_pk_bf16_f32 -> 32 ds_write_b32
//      (was 256 VALU + 64 ds_write_b16). Swizzle now at int granularity:
//      int index (P ^ (ci&7)), P = s/2. Same bank spread (16/instr).
//  (3) GEMM1: 2 x ds_read_b64 per MFMA + compile-time permute
//      bx.i[m] = D[m ^ (i&3)], base int = (lq2*4) ^ (i&4).
//  (4) a2 fragments come prepacked bf16 from k_prep (wvb): 8 coalesced 16B
//      loads, zero convert VALU; issued right after staging loads so their
//      HBM latency hides under GEMM1.
//  rc (residual) read from xs between barriers, b64 + compile-time r&1 swap.
// ---------------------------------------------------------------------------
__global__ __launch_bounds__(256, 3)
void k_mix(const float* __restrict__ x, const float* __restrict__ heat,
           const short* __restrict__ wvb, const float* __restrict__ bv,
           const float* __restrict__ gam, float* __restrict__ out) {
  __shared__ __attribute__((aligned(16))) short sm[20480];  // 40 KB union

  const int b    = blockIdx.y;
  const int hw0  = blockIdx.x * 16;
  const int tid  = threadIdx.x;
  const int lane = tid & 63;
  const int w    = tid >> 6;      // wave 0..3
  const int l15  = lane & 15;
  const int lq   = lane >> 4;     // quarter 0..3

  union U8 { s16x8 v; int i[4]; unsigned u[4]; };
  const f32x4 fz = {0.f, 0.f, 0.f, 0.f};

  // ---- A1 fragment first (needed by GEMM1; hides under staging loads) ----
  U8 ha; ha.i[0] = ha.i[1] = ha.i[2] = ha.i[3] = 0;
  if (lane < 32) {
    const float* hp = heat + b * 256 + l15 * 16 + lq * 8;
    float4 h0 = *(const float4*)hp;
    float4 h1 = *(const float4*)(hp + 4);
    ha.u[0] = pkbf(h0.x, h0.y); ha.u[1] = pkbf(h0.z, h0.w);
    ha.u[2] = pkbf(h1.x, h1.y); ha.u[3] = pkbf(h1.z, h1.w);
  }

  // ---- stage x tile -> bf16 xs: row (ci*16+g), stride 20 shorts,
  //      s-pairs packed as ints at int-index (P ^ (ci&7)) ------------------
  {
    const int ci = tid >> 2, q = tid & 3;
    const int sx = ci & 7;
    const float* xp = x + ((size_t)b * T_ * C_ + ci) * HW_ + hw0 + q * 4;
    short* r0 = &sm[(ci * 16 + q * 4) * 20];
#pragma unroll
    for (int P = 0; P < 8; ++P) {
      float4 v0 = *(const float4*)(xp + (size_t)(2 * P) * C_ * HW_);
      float4 v1 = *(const float4*)(xp + (size_t)(2 * P + 1) * C_ * HW_);
      const int ip = (P ^ sx) * 2;    // short offset, 4B-aligned
      *(unsigned*)&r0[ip]      = pkbf(v0.x, v1.x);
      *(unsigned*)&r0[20 + ip] = pkbf(v0.y, v1.y);
      *(unsigned*)&r0[40 + ip] = pkbf(v0.z, v1.z);
      *(unsigned*)&r0[60 + ip] = pkbf(v0.w, v1.w);
    }
  }

  // ---- a2 fragments (prepacked bf16), issued now, consumed after GEMM1 ---
  U8 a2[8];
#pragma unroll
  for (int fr = 0; fr < 8; ++fr)
    a2[fr].v = *(const s16x8*)&wvb[(fr * 64 + lane) * 8];

  // wave-local: my staging writes are the only rows my GEMM1 reads
  asm volatile("s_waitcnt lgkmcnt(0)" ::: "memory");

  // ---- GEMM1: 16 MFMAs, ci = w*16+i (own staged rows, no barrier) --------
  // c1[i]: lane holds xh[t=(lq*4+reg)][ci=w*16+i][g=l15]
  const int lq2 = lq & 1;   // lanes lq>=2 alias lq-2's B rows (A there is 0)
  f32x4 c1[16];
#pragma unroll
  for (int i = 0; i < 16; ++i) {
    const int ci = w * 16 + i;
    const short* row = &sm[(ci * 16 + l15) * 20];
    const int base = (lq2 * 4) ^ (i & 4);          // int index, even
    int2 D0 = *(const int2*)&row[2 * base];        // ints base, base+1
    int2 D1 = *(const int2*)&row[2 * base + 4];    // ints base+2, base+3
    U8 bx;
    const int t3 = i & 3;                          // compile-time per iter
    bx.i[0] = (t3 == 0) ? D0.x : (t3 == 1) ? D0.y : (t3 == 2) ? D1.x : D1.y;
    bx.i[1] = (t3 == 0) ? D0.y : (t3 == 1) ? D0.x : (t3 == 2) ? D1.y : D1.x;
    bx.i[2] = (t3 == 0) ? D1.x : (t3 == 1) ? D1.y : (t3 == 2) ? D0.x : D0.y;
    bx.i[3] = (t3 == 0) ? D1.y : (t3 == 1) ? D1.x : (t3 == 2) ? D0.y : D0.x;
    c1[i] = __builtin_amdgcn_mfma_f32_16x16x32_bf16(ha.v, bx.v, fz, 0, 0, 0);
  }
  __syncthreads();   // all staging complete -> rc may read any row

  // ---- residual from LDS (xs): rc[(ct*4+r)*2+h] = int holding bf16 pair
  //      (t = w*4+2h, w*4+2h+1) for c = ct*16+lq*4+r, g = l15 --------------
  unsigned rc[32];
#pragma unroll
  for (int ct = 0; ct < 4; ++ct)
#pragma unroll
    for (int r = 0; r < 4; ++r) {
      const int c = ct * 16 + lq * 4 + r;
      const short* row = &sm[(c * 16 + l15) * 20];
      // X = (lq&1)*4 + r ; base = ((w*2) ^ X) & ~1 ; phys(h) = base|(h^(r&1))
      const int base = 4 * ((w >> 1) ^ (lq & 1)) + 2 * ((w & 1) ^ (r >> 1));
      int2 D = *(const int2*)&row[2 * base];
      rc[(ct * 4 + r) * 2 + 0] = (r & 1) ? (unsigned)D.y : (unsigned)D.x;
      rc[(ct * 4 + r) * 2 + 1] = (r & 1) ? (unsigned)D.x : (unsigned)D.y;
    }
  __syncthreads();   // all xs reads done; sm becomes xh

  // ---- write xh -> LDS [n=t*16+g][ci] (stride 72), ci-pairs cvt_pk'd -----
#pragma unroll
  for (int r = 0; r < 4; ++r) {
    const int t = lq * 4 + r;
    short* dst = &sm[(t * 16 + l15) * 72 + w * 16];
    u32x4 p0, p1;
    p0[0] = pkbf(c1[0][r],  c1[1][r]);  p0[1] = pkbf(c1[2][r],  c1[3][r]);
    p0[2] = pkbf(c1[4][r],  c1[5][r]);  p0[3] = pkbf(c1[6][r],  c1[7][r]);
    p1[0] = pkbf(c1[8][r],  c1[9][r]);  p1[1] = pkbf(c1[10][r], c1[11][r]);
    p1[2] = pkbf(c1[12][r], c1[13][r]); p1[3] = pkbf(c1[14][r], c1[15][r]);
    *(u32x4*)dst       = p0;
    *(u32x4*)(dst + 8) = p1;
  }

  f32x4 bvr[4];
#pragma unroll
  for (int ct = 0; ct < 4; ++ct)
    bvr[ct] = *(const f32x4*)(bv + ct * 16 + lq * 4);
  const float gamma = gam[0];
  __syncthreads();   // xh visible

  // ---- GEMM2 + epilogue: this wave owns t = w*4 .. w*4+3 ------------------
#pragma unroll
  for (int ntq = 0; ntq < 4; ++ntq) {
    const int t = w * 4 + ntq;
    const short* xr0 = &sm[(t * 16 + l15) * 72];
    s16x8 b0 = *(const s16x8*)(xr0 + lq * 8);        // k = ci   0..31 slice
    s16x8 b1 = *(const s16x8*)(xr0 + 32 + lq * 8);   // k = ci  32..63 slice
    float* op = out + ((size_t)(b * T_ + t) * C_) * HW_ + hw0 + l15;
    const int half = ntq >> 1, odd = ntq & 1;
#pragma unroll
    for (int ct = 0; ct < 4; ++ct) {
      f32x4 acc = __builtin_amdgcn_mfma_f32_16x16x32_bf16(a2[ct * 2 + 0].v, b0, fz, 0, 0, 0);
      acc = __builtin_amdgcn_mfma_f32_16x16x32_bf16(a2[ct * 2 + 1].v, b1, acc, 0, 0, 0);
      const int cb = ct * 16 + lq * 4;
#pragma unroll
      for (int r = 0; r < 4; ++r) {
        const unsigned v = rc[(ct * 4 + r) * 2 + half];
        union { unsigned u; float f; } z;
        z.u = odd ? (v & 0xffff0000u) : (v << 16);
        op[(size_t)(cb + r) * HW_] = gamma * (acc[r] + bvr[ct][r]) + z.f;
      }
    }
  }
}

// ---------------------------------------------------------------------------
extern "C" void kernel_launch(void* const* d_in, const int* in_sizes, int n_in,
                              void* d_out, int out_size, void* d_ws, size_t ws_size,
                              hipStream_t stream) {
  const float* x   = (const float*)d_in[0];
  const float* wq  = (const float*)d_in[1];
  const float* bq  = (const float*)d_in[2];
  const float* wk  = (const float*)d_in[3];
  const float* bk  = (const float*)d_in[4];
  const float* wv  = (const float*)d_in[5];
  const float* bv  = (const float*)d_in[6];
  const float* gam = (const float*)d_in[7];
  float* out = (float*)d_out;

  float* WT    = (float*)d_ws;                        // 2*64*32 = 4096 floats
  short* wvb   = (short*)(WT + 4096);                 // 4096 bf16 = 2048 floats
  float* partE = WT + 4096 + 2048;                    // 4*288*256 floats
  float* heat  = partE + (size_t)B_ * NCHUNK_ * 256;  // 4*256 floats

  k_prep   <<<1, 256, 0, stream>>>(wq, wk, wv, WT, wvb);
  k_energy <<<dim3(NCHUNK_, B_), 512, 0, stream>>>(x, WT, bq, bk, partE);
  k_softmax<<<dim3(B_),          256, 0, stream>>>(partE, heat);
  k_mix    <<<dim3(HW_ / 16, B_), 256, 0, stream>>>(x, heat, wvb, bv, gam, out);
}

// Round 9
// 169.167 us; speedup vs baseline: 1.3611x; 1.0373x over previous
//
#include <hip/hip_runtime.h>
#include <math.h>

#define B_  4
#define T_  16
#define C_  64
#define CQ_ 8
#define HW_ 9216          // 96*96
#define NCH2_ 144         // HW_/64 energy chunks

typedef __attribute__((ext_vector_type(8))) short    s16x8;  // 8 bf16
typedef __attribute__((ext_vector_type(4))) float    f32x4;
typedef __attribute__((ext_vector_type(4))) unsigned u32x4;

static __device__ __forceinline__ short f2bf(float f) {
  union { float f; unsigned u; } v; v.f = f;
  return (short)((v.u + 0x7FFFu + ((v.u >> 16) & 1u)) >> 16);  // RNE
}
static __device__ __forceinline__ unsigned pkbf(float lo, float hi) {
  unsigned r;
  asm("v_cvt_pk_bf16_f32 %0, %1, %2" : "=v"(r) : "v"(lo), "v"(hi));
  return r;   // low16 = bf16(lo), high16 = bf16(hi)
}
static __device__ __forceinline__ float ubf(unsigned u) {
  union { unsigned u; float f; } v; v.u = u; return v.f;
}

// ---------------------------------------------------------------------------
// k_prep: (a) transpose conv weights for k_energy scalar loads;
//         (b) prepack Wv to bf16 in GEMM2 A-fragment order.
// ---------------------------------------------------------------------------
__global__ __launch_bounds__(256)
void k_prep(const float* __restrict__ wq, const float* __restrict__ wk,
            const float* __restrict__ wv, float* __restrict__ WT,
            short* __restrict__ wvb) {
  for (int j = threadIdx.x; j < CQ_ * C_ * 3; j += 256) {
    int ci = j / 24, r = j % 24;      // r = cqi*3 + d
    int cqi = r / 3, d = r % 3;
    WT[ci * 32 + r]        = wq[(cqi * C_ + ci) * 3 + d];
    WT[2048 + ci * 32 + r] = wk[(cqi * C_ + ci) * 3 + d];
  }
  for (int idx = threadIdx.x; idx < 4096; idx += 256) {
    int j = idx & 7, lane = (idx >> 3) & 63, fr = idx >> 9;  // fr = ct*2+ks
    int ct = fr >> 1, ks = fr & 1;
    int c  = ct * 16 + (lane & 15);
    int ci = ks * 32 + (lane >> 4) * 8 + j;
    wvb[idx] = f2bf(wv[c * C_ + ci]);
  }
}

// ---------------------------------------------------------------------------
// k_energy (round 9): grid (144, 4), block 512 = (t=16 x gq=32), 2 g/thread.
// Phase 1 (exact fp32 conv): thread (t,gq) computes q,k[8] for g=2gq,2gq+1
//   via float2 x-loads (3 taps/ci) and s_load'ed weights. 2x FMA per fetched
//   weight/x vs round 8.
// Phase 2: split q,k into hi/lo bf16 planes (q = qh + ql exact to ~2^-18)
//   and stage into QKs[qk][plane][t][cq][g64], 16B-chunk XOR-swizzled by t
//   (writes b32 conflict-free; frag reads b128 bank-balanced).
// Phase 3 (MFMA E-dot): E[t,s] = Qh·Kh + Qh·Kl + Ql·Kh over K=512 (cq,g).
//   8 waves x 2 k-steps x 3 MFMA; fragment layout identical to the verified
//   k_mix GEMM2 pattern (A row = lane&15 = t, B col = lane&15 = s,
//   k = ks*32 + (lane>>4)*8 + j; same-formula k-map cancels).
//   Partials reduced in LDS, written to partE (fp32) for k_softmax.
// ---------------------------------------------------------------------------
__global__ __launch_bounds__(512, 4)
void k_energy(const float* __restrict__ x, const float* __restrict__ WT,
              const float* __restrict__ bq, const float* __restrict__ bk,
              float* __restrict__ partE) {
  __shared__ __attribute__((aligned(16))) short QKs[32768];  // 64 KB
  __shared__ float Ered[8 * 256];                            // 8 KB

  const int b   = blockIdx.y;
  const int hw0 = blockIdx.x * 64;
  const int tid = threadIdx.x;
  const int t   = tid >> 5;         // 0..15
  const int gq  = tid & 31;         // 0..31, owns g = 2gq, 2gq+1

  const float* xb  = x + (size_t)(b * T_ * C_) * HW_ + hw0 + 2 * gq;
  const float* wqt = WT;            // [ci*32 + cqi*3 + d]
  const float* wkt = WT + 2048;

  float2 qa[CQ_], ka[CQ_];
#pragma unroll
  for (int j = 0; j < CQ_; ++j) {
    qa[j].x = qa[j].y = 0.f; ka[j].x = ka[j].y = 0.f;
  }

#pragma unroll 2
  for (int ci = 0; ci < C_; ++ci) {
    float2 xm = {0.f, 0.f}, xp = {0.f, 0.f};
    if (t > 0)      xm = *(const float2*)(xb + (size_t)((t - 1) * C_ + ci) * HW_);
    float2 x0 =          *(const float2*)(xb + (size_t)(t * C_ + ci) * HW_);
    if (t < T_ - 1) xp = *(const float2*)(xb + (size_t)((t + 1) * C_ + ci) * HW_);
    const float* wq_r = &wqt[ci * 32];
    const float* wk_r = &wkt[ci * 32];
#pragma unroll
    for (int j = 0; j < CQ_; ++j) {
      const float a0 = wq_r[j * 3 + 0], a1 = wq_r[j * 3 + 1], a2 = wq_r[j * 3 + 2];
      qa[j].x += a0 * xm.x + a1 * x0.x + a2 * xp.x;
      qa[j].y += a0 * xm.y + a1 * x0.y + a2 * xp.y;
      const float c0 = wk_r[j * 3 + 0], c1 = wk_r[j * 3 + 1], c2 = wk_r[j * 3 + 2];
      ka[j].x += c0 * xm.x + c1 * x0.x + c2 * xp.x;
      ka[j].y += c0 * xm.y + c1 * x0.y + c2 * xp.y;
    }
  }

  // ---- bias + hi/lo split + swizzled LDS stage ---------------------------
  // QKs plane bases (shorts): Qh 0, Ql 8192, Kh 16384, Kl 24576.
  // cell(t,cq,g): (t*8+cq)*64 + ((g>>3) ^ (t&7))*8 + (g&7)
  const int gof = ((gq >> 2) ^ (t & 7)) * 8 + 2 * (gq & 3);
#pragma unroll
  for (int j = 0; j < CQ_; ++j) {
    const float q0 = qa[j].x + bq[j], q1 = qa[j].y + bq[j];
    const float k0 = ka[j].x + bk[j], k1 = ka[j].y + bk[j];
    const unsigned qh = pkbf(q0, q1);
    const unsigned ql = pkbf(q0 - ubf(qh << 16), q1 - ubf(qh & 0xffff0000u));
    const unsigned kh = pkbf(k0, k1);
    const unsigned kl = pkbf(k0 - ubf(kh << 16), k1 - ubf(kh & 0xffff0000u));
    const int rb = (t * 8 + j) * 64 + gof;
    *(unsigned*)&QKs[rb]         = qh;
    *(unsigned*)&QKs[8192 + rb]  = ql;
    *(unsigned*)&QKs[16384 + rb] = kh;
    *(unsigned*)&QKs[24576 + rb] = kl;
  }
  __syncthreads();

  // ---- MFMA E-dot: wave w covers ks = 2w, 2w+1 ---------------------------
  const int lane = tid & 63, w = tid >> 6;
  const int l15  = lane & 15, lq = lane >> 4;
  f32x4 acc = {0.f, 0.f, 0.f, 0.f};
#pragma unroll
  for (int kk = 0; kk < 2; ++kk) {
    const int ks = w * 2 + kk;
    const int cq = ks >> 1;
    const int g0 = (ks & 1) * 32 + lq * 8;
    const int rb = (l15 * 8 + cq) * 64 + (((g0 >> 3) ^ (l15 & 7)) << 3);
    s16x8 fqh = *(const s16x8*)&QKs[rb];
    s16x8 fql = *(const s16x8*)&QKs[8192 + rb];
    s16x8 fkh = *(const s16x8*)&QKs[16384 + rb];
    s16x8 fkl = *(const s16x8*)&QKs[24576 + rb];
    acc = __builtin_amdgcn_mfma_f32_16x16x32_bf16(fqh, fkh, acc, 0, 0, 0);
    acc = __builtin_amdgcn_mfma_f32_16x16x32_bf16(fqh, fkl, acc, 0, 0, 0);
    acc = __builtin_amdgcn_mfma_f32_16x16x32_bf16(fql, fkh, acc, 0, 0, 0);
  }
#pragma unroll
  for (int r = 0; r < 4; ++r)
    Ered[w * 256 + (lq * 4 + r) * 16 + l15] = acc[r];
  __syncthreads();

  if (tid < 256) {
    float e = 0.f;
#pragma unroll
    for (int ww = 0; ww < 8; ++ww) e += Ered[ww * 256 + tid];
    partE[((size_t)(b * NCH2_ + blockIdx.x)) * 256 + tid] = e;
  }
}

// ---------------------------------------------------------------------------
// k_softmax: reduce 144 partials and softmax over s. grid 4, block 256.
// ---------------------------------------------------------------------------
__global__ __launch_bounds__(256)
void k_softmax(const float* __restrict__ partE, float* __restrict__ heat) {
  const int b = blockIdx.x;
  const int tid = threadIdx.x;
  float e = 0.f;
  for (int ch = 0; ch < NCH2_; ++ch)
    e += partE[((size_t)(b * NCH2_ + ch)) * 256 + tid];
  float mx = e;
#pragma unroll
  for (int m = 1; m < 16; m <<= 1) mx = fmaxf(mx, __shfl_xor(mx, m, 64));
  float ex = expf(e - mx);
  float sm = ex;
#pragma unroll
  for (int m = 1; m < 16; m <<= 1) sm += __shfl_xor(sm, m, 64);
  heat[b * 256 + tid] = ex / sm;
}

// ---------------------------------------------------------------------------
// k_mix (MFMA, unchanged from round 8): out = gamma*(Wv@(heat@X)) + bias + res
// ---------------------------------------------------------------------------
__global__ __launch_bounds__(256, 3)
void k_mix(const float* __restrict__ x, const float* __restrict__ heat,
           const short* __restrict__ wvb, const float* __restrict__ bv,
           const float* __restrict__ gam, float* __restrict__ out) {
  __shared__ __attribute__((aligned(16))) short sm[20480];  // 40 KB union

  const int b    = blockIdx.y;
  const int hw0  = blockIdx.x * 16;
  const int tid  = threadIdx.x;
  const int lane = tid & 63;
  const int w    = tid >> 6;      // wave 0..3
  const int l15  = lane & 15;
  const int lq   = lane >> 4;     // quarter 0..3

  union U8 { s16x8 v; int i[4]; unsigned u[4]; };
  const f32x4 fz = {0.f, 0.f, 0.f, 0.f};

  // ---- A1 fragment first (needed by GEMM1; hides under staging loads) ----
  U8 ha; ha.i[0] = ha.i[1] = ha.i[2] = ha.i[3] = 0;
  if (lane < 32) {
    const float* hp = heat + b * 256 + l15 * 16 + lq * 8;
    float4 h0 = *(const float4*)hp;
    float4 h1 = *(const float4*)(hp + 4);
    ha.u[0] = pkbf(h0.x, h0.y); ha.u[1] = pkbf(h0.z, h0.w);
    ha.u[2] = pkbf(h1.x, h1.y); ha.u[3] = pkbf(h1.z, h1.w);
  }

  // ---- stage x tile -> bf16 xs: row (ci*16+g), stride 20 shorts,
  //      s-pairs packed as ints at int-index (P ^ (ci&7)) ------------------
  {
    const int ci = tid >> 2, q = tid & 3;
    const int sx = ci & 7;
    const float* xp = x + ((size_t)b * T_ * C_ + ci) * HW_ + hw0 + q * 4;
    short* r0 = &sm[(ci * 16 + q * 4) * 20];
#pragma unroll
    for (int P = 0; P < 8; ++P) {
      float4 v0 = *(const float4*)(xp + (size_t)(2 * P) * C_ * HW_);
      float4 v1 = *(const float4*)(xp + (size_t)(2 * P + 1) * C_ * HW_);
      const int ip = (P ^ sx) * 2;    // short offset, 4B-aligned
      *(unsigned*)&r0[ip]      = pkbf(v0.x, v1.x);
      *(unsigned*)&r0[20 + ip] = pkbf(v0.y, v1.y);
      *(unsigned*)&r0[40 + ip] = pkbf(v0.z, v1.z);
      *(unsigned*)&r0[60 + ip] = pkbf(v0.w, v1.w);
    }
  }

  // ---- a2 fragments (prepacked bf16), issued now, consumed after GEMM1 ---
  U8 a2[8];
#pragma unroll
  for (int fr = 0; fr < 8; ++fr)
    a2[fr].v = *(const s16x8*)&wvb[(fr * 64 + lane) * 8];

  // wave-local: my staging writes are the only rows my GEMM1 reads
  asm volatile("s_waitcnt lgkmcnt(0)" ::: "memory");

  // ---- GEMM1: 16 MFMAs, ci = w*16+i (own staged rows, no barrier) --------
  const int lq2 = lq & 1;   // lanes lq>=2 alias lq-2's B rows (A there is 0)
  f32x4 c1[16];
#pragma unroll
  for (int i = 0; i < 16; ++i) {
    const int ci = w * 16 + i;
    const short* row = &sm[(ci * 16 + l15) * 20];
    const int base = (lq2 * 4) ^ (i & 4);          // int index, even
    int2 D0 = *(const int2*)&row[2 * base];        // ints base, base+1
    int2 D1 = *(const int2*)&row[2 * base + 4];    // ints base+2, base+3
    U8 bx;
    const int t3 = i & 3;                          // compile-time per iter
    bx.i[0] = (t3 == 0) ? D0.x : (t3 == 1) ? D0.y : (t3 == 2) ? D1.x : D1.y;
    bx.i[1] = (t3 == 0) ? D0.y : (t3 == 1) ? D0.x : (t3 == 2) ? D1.y : D1.x;
    bx.i[2] = (t3 == 0) ? D1.x : (t3 == 1) ? D1.y : (t3 == 2) ? D0.x : D0.y;
    bx.i[3] = (t3 == 0) ? D1.y : (t3 == 1) ? D1.x : (t3 == 2) ? D0.y : D0.x;
    c1[i] = __builtin_amdgcn_mfma_f32_16x16x32_bf16(ha.v, bx.v, fz, 0, 0, 0);
  }
  __syncthreads();   // all staging complete -> rc may read any row

  // ---- residual from LDS (xs): rc[(ct*4+r)*2+h] = int holding bf16 pair
  unsigned rc[32];
#pragma unroll
  for (int ct = 0; ct < 4; ++ct)
#pragma unroll
    for (int r = 0; r < 4; ++r) {
      const int c = ct * 16 + lq * 4 + r;
      const short* row = &sm[(c * 16 + l15) * 20];
      const int base = 4 * ((w >> 1) ^ (lq & 1)) + 2 * ((w & 1) ^ (r >> 1));
      int2 D = *(const int2*)&row[2 * base];
      rc[(ct * 4 + r) * 2 + 0] = (r & 1) ? (unsigned)D.y : (unsigned)D.x;
      rc[(ct * 4 + r) * 2 + 1] = (r & 1) ? (unsigned)D.x : (unsigned)D.y;
    }
  __syncthreads();   // all xs reads done; sm becomes xh

  // ---- write xh -> LDS [n=t*16+g][ci] (stride 72), ci-pairs cvt_pk'd -----
#pragma unroll
  for (int r = 0; r < 4; ++r) {
    const int t = lq * 4 + r;
    short* dst = &sm[(t * 16 + l15) * 72 + w * 16];
    u32x4 p0, p1;
    p0[0] = pkbf(c1[0][r],  c1[1][r]);  p0[1] = pkbf(c1[2][r],  c1[3][r]);
    p0[2] = pkbf(c1[4][r],  c1[5][r]);  p0[3] = pkbf(c1[6][r],  c1[7][r]);
    p1[0] = pkbf(c1[8][r],  c1[9][r]);  p1[1] = pkbf(c1[10][r], c1[11][r]);
    p1[2] = pkbf(c1[12][r], c1[13][r]); p1[3] = pkbf(c1[14][r], c1[15][r]);
    *(u32x4*)dst       = p0;
    *(u32x4*)(dst + 8) = p1;
  }

  f32x4 bvr[4];
#pragma unroll
  for (int ct = 0; ct < 4; ++ct)
    bvr[ct] = *(const f32x4*)(bv + ct * 16 + lq * 4);
  const float gamma = gam[0];
  __syncthreads();   // xh visible

  // ---- GEMM2 + epilogue: this wave owns t = w*4 .. w*4+3 ------------------
#pragma unroll
  for (int ntq = 0; ntq < 4; ++ntq) {
    const int t = w * 4 + ntq;
    const short* xr0 = &sm[(t * 16 + l15) * 72];
    s16x8 b0 = *(const s16x8*)(xr0 + lq * 8);        // k = ci   0..31 slice
    s16x8 b1 = *(const s16x8*)(xr0 + 32 + lq * 8);   // k = ci  32..63 slice
    float* op = out + ((size_t)(b * T_ + t) * C_) * HW_ + hw0 + l15;
    const int half = ntq >> 1, odd = ntq & 1;
#pragma unroll
    for (int ct = 0; ct < 4; ++ct) {
      f32x4 acc = __builtin_amdgcn_mfma_f32_16x16x32_bf16(a2[ct * 2 + 0].v, b0, fz, 0, 0, 0);
      acc = __builtin_amdgcn_mfma_f32_16x16x32_bf16(a2[ct * 2 + 1].v, b1, acc, 0, 0, 0);
      const int cb = ct * 16 + lq * 4;
#pragma unroll
      for (int r = 0; r < 4; ++r) {
        const unsigned v = rc[(ct * 4 + r) * 2 + half];
        union { unsigned u; float f; } z;
        z.u = odd ? (v & 0xffff0000u) : (v << 16);
        op[(size_t)(cb + r) * HW_] = gamma * (acc[r] + bvr[ct][r]) + z.f;
      }
    }
  }
}

// ---------------------------------------------------------------------------
extern "C" void kernel_launch(void* const* d_in, const int* in_sizes, int n_in,
                              void* d_out, int out_size, void* d_ws, size_t ws_size,
                              hipStream_t stream) {
  const float* x   = (const float*)d_in[0];
  const float* wq  = (const float*)d_in[1];
  const float* bq  = (const float*)d_in[2];
  const float* wk  = (const float*)d_in[3];
  const float* bk  = (const float*)d_in[4];
  const float* wv  = (const float*)d_in[5];
  const float* bv  = (const float*)d_in[6];
  const float* gam = (const float*)d_in[7];
  float* out = (float*)d_out;

  float* WT    = (float*)d_ws;                        // 4096 floats
  short* wvb   = (short*)(WT + 4096);                 // 4096 bf16
  float* partE = WT + 4096 + 2048;                    // 4*144*256 floats
  float* heat  = partE + (size_t)B_ * NCH2_ * 256;    // 4*256 floats

  k_prep   <<<1, 256, 0, stream>>>(wq, wk, wv, WT, wvb);
  k_energy <<<dim3(NCH2_, B_), 512, 0, stream>>>(x, WT, bq, bk, partE);
  k_softmax<<<dim3(B_),        256, 0, stream>>>(partE, heat);
  k_mix    <<<dim3(HW_ / 16, B_), 256, 0, stream>>>(x, heat, wvb, bv, gam, out);
}

// Round 10
// 153.755 us; speedup vs baseline: 1.4975x; 1.1002x over previous
//
#include <hip/hip_runtime.h>
#include <math.h>

#define B_  4
#define T_  16
#define C_  64
#define CQ_ 8
#define HW_ 9216          // 96*96
#define NCH_ 576          // HW_/16 energy chunks

typedef __attribute__((ext_vector_type(8))) short    s16x8;  // 8 bf16
typedef __attribute__((ext_vector_type(4))) float    f32x4;
typedef __attribute__((ext_vector_type(4))) unsigned u32x4;

static __device__ __forceinline__ short f2bf(float f) {
  union { float f; unsigned u; } v; v.f = f;
  return (short)((v.u + 0x7FFFu + ((v.u >> 16) & 1u)) >> 16);  // RNE
}
static __device__ __forceinline__ unsigned pkbf(float lo, float hi) {
  unsigned r;
  asm("v_cvt_pk_bf16_f32 %0, %1, %2" : "=v"(r) : "v"(lo), "v"(hi));
  return r;   // low16 = bf16(lo), high16 = bf16(hi)
}
static __device__ __forceinline__ float ubf(unsigned u) {
  union { unsigned u; float f; } v; v.u = u; return v.f;
}

// ---------------------------------------------------------------------------
// k_prep: (a) prepack conv weights as MFMA A-fragments (bf16):
//   k-map: k = ks*32 + lq*8 + j -> d = ks>>1, ci = (ks&1)*32 + lq*8 + j
//   m = lane&15: m<8 -> wq row cq=m ; m>=8 -> wk row cq=m-8
//   wqkb[(ks*64 + lane)*8 + j]
//         (b) prepack Wv to bf16 in k_mix GEMM2 A-fragment order (wvb).
// ---------------------------------------------------------------------------
__global__ __launch_bounds__(256)
void k_prep(const float* __restrict__ wq, const float* __restrict__ wk,
            const float* __restrict__ wv, short* __restrict__ wqkb,
            short* __restrict__ wvb) {
  for (int idx = threadIdx.x; idx < 3072; idx += 256) {
    int j = idx & 7, lane = (idx >> 3) & 63, ks = idx >> 9;
    int m = lane & 15, lq = lane >> 4;
    int ci = (ks & 1) * 32 + lq * 8 + j;
    int d  = ks >> 1;
    float wval = (m < 8) ? wq[(m * C_ + ci) * 3 + d]
                         : wk[((m - 8) * C_ + ci) * 3 + d];
    wqkb[idx] = f2bf(wval);
  }
  for (int idx = threadIdx.x; idx < 4096; idx += 256) {
    int j = idx & 7, lane = (idx >> 3) & 63, fr = idx >> 9;  // fr = ct*2+ks
    int ct = fr >> 1, ks = fr & 1;
    int c  = ct * 16 + (lane & 15);
    int ci = ks * 32 + (lane >> 4) * 8 + j;
    wvb[idx] = f2bf(wv[c * C_ + ci]);
  }
}

// ---------------------------------------------------------------------------
// k_energy (round 10, all-MFMA): grid (576, 4), block 512 (8 waves).
// Phase 0: zero pad rows (s=-1, s=16) -> branch-free conv padding.
// Phase 1: stage x[b, :, :, 16g] -> bf16 xs[(s+1)*16+g][ci], stride 72 sh,
//          ci-chunk (8ci=16B) XOR-swizzled by (s+1)&7. ci-pairs via cvt_pk.
// Phase 2: conv GEMM per wave (g = 2w, 2w+1): D[m=(qk,cq)][n=t] =
//          sum_k W'[m][k] x[t+d-1,ci,g], K=192, 6 MFMA. fp32 bias, hi/lo
//          split (q = qh + ql exact to ~2^-17), write 4 planes Qh/Ql/Kh/Kl
//          [t][g*8+cq] stride 136.
// Phase 3: E-dot waves 0-3 (eks=w): E[t][s] = Qh·Kh + Qh·Kl + Ql·Kh over
//          K=128 (g,cq). LDS-reduce 4 partials -> partE.
// All fragment conventions copied from the verified k_mix GEMM2 pattern
// (A row m = lane&15; B col n = lane&15; k = ks*32+lq*8+j both sides;
//  D: row = lq*4+reg, col = lane&15).
// ---------------------------------------------------------------------------
__global__ __launch_bounds__(512, 4)
void k_energy(const float* __restrict__ x, const short* __restrict__ wqkb,
              const float* __restrict__ bq, const float* __restrict__ bk,
              float* __restrict__ partE) {
  __shared__ __attribute__((aligned(16))) short sh[29440];  // xs 20736 + qk 8704
  __shared__ float Ered[1024];

  const int b    = blockIdx.y;
  const int hw0  = blockIdx.x * 16;
  const int tid  = threadIdx.x;
  const int lane = tid & 63, w = tid >> 6;
  const int l15  = lane & 15, lq = lane >> 4;
  const f32x4 fz = {0.f, 0.f, 0.f, 0.f};

  // phase 0: zero rows 0..15 (u32 [0,576)) and 272..287 (u32 [9792,10368))
  for (int i = tid; i < 1152; i += 512)
    ((unsigned*)sh)[(i < 576) ? i : (9216 + i)] = 0;

  // A-frags (conv weights), coalesced 16B/lane
  s16x8 afr[6];
#pragma unroll
  for (int ks = 0; ks < 6; ++ks)
    afr[ks] = *(const s16x8*)&wqkb[(ks * 64 + lane) * 8];

  // bias for my 4 output rows m = lq*4+r  (m<8 -> q/bq, else k/bk)
  const float* bias = (lq < 2) ? bq : bk;
  const int cqb = (lq & 1) * 4;
  const float b0 = bias[cqb + 0], b1 = bias[cqb + 1];
  const float b2 = bias[cqb + 2], b3 = bias[cqb + 3];

  // phase 1: stage. thread = (s0, cp, q4); 8 float4 loads, 16 b32 writes.
  {
    const int q4 = tid & 3;          // g quad
    const int cp = (tid >> 2) & 31;  // ci pair (ci = 2cp, 2cp+1)
    const int s0 = tid >> 7;         // 0..3
    const float* xb = x + (size_t)(b * T_ * C_ + 2 * cp) * HW_ + hw0 + 4 * q4;
#pragma unroll
    for (int it = 0; it < 4; ++it) {
      const int s = s0 * 4 + it;
      float4 v0 = *(const float4*)(xb + (size_t)(s * C_) * HW_);
      float4 v1 = *(const float4*)(xb + (size_t)(s * C_) * HW_ + HW_);
      const int off = ((cp >> 2) ^ ((s + 1) & 7)) * 8 + 2 * (cp & 3);
      const int rb  = (s + 1) * 16 + 4 * q4;
      *(unsigned*)&sh[(rb + 0) * 72 + off] = pkbf(v0.x, v1.x);
      *(unsigned*)&sh[(rb + 1) * 72 + off] = pkbf(v0.y, v1.y);
      *(unsigned*)&sh[(rb + 2) * 72 + off] = pkbf(v0.z, v1.z);
      *(unsigned*)&sh[(rb + 3) * 72 + off] = pkbf(v0.w, v1.w);
    }
  }
  __syncthreads();

  // phase 2: conv GEMM, wave w -> g = 2w, 2w+1
#pragma unroll
  for (int gl = 0; gl < 2; ++gl) {
    const int g = w * 2 + gl;
    f32x4 a = fz;
#pragma unroll
    for (int ks = 0; ks < 6; ++ks) {
      const int d = ks >> 1;
      const int row = (l15 + d) * 16 + g;           // s+1 = t+d
      const int chunk = (((ks & 1) * 4 + lq) ^ ((l15 + d) & 7));
      s16x8 bf = *(const s16x8*)&sh[row * 72 + chunk * 8];
      a = __builtin_amdgcn_mfma_f32_16x16x32_bf16(afr[ks], bf, a, 0, 0, 0);
    }
    const float v0 = a[0] + b0, v1 = a[1] + b1;
    const float v2 = a[2] + b2, v3 = a[3] + b3;
    const unsigned h01 = pkbf(v0, v1), h23 = pkbf(v2, v3);
    const unsigned l01 = pkbf(v0 - ubf(h01 << 16), v1 - ubf(h01 & 0xffff0000u));
    const unsigned l23 = pkbf(v2 - ubf(h23 << 16), v3 - ubf(h23 & 0xffff0000u));
    // planes (shorts): Qh 20736, Ql +2176, Kh +4352, Kl +6528
    short* pl = &sh[20736 + (lq >> 1) * 4352 + l15 * 136 + g * 8 + (lq & 1) * 4];
    uint2 hh; hh.x = h01; hh.y = h23;
    uint2 ll; ll.x = l01; ll.y = l23;
    *(uint2*)pl          = hh;
    *(uint2*)(pl + 2176) = ll;
  }
  __syncthreads();

  // phase 3: E-dot, waves 0..3 take k-step eks = w (K = 128 over (g,cq))
  if (w < 4) {
    const int off = l15 * 136 + w * 32 + lq * 8;
    const short* Qp = &sh[20736];
    const short* Kp = &sh[20736 + 4352];
    s16x8 qh = *(const s16x8*)&Qp[off];
    s16x8 ql = *(const s16x8*)&Qp[off + 2176];
    s16x8 kh = *(const s16x8*)&Kp[off];
    s16x8 kl = *(const s16x8*)&Kp[off + 2176];
    f32x4 e = fz;
    e = __builtin_amdgcn_mfma_f32_16x16x32_bf16(qh, kh, e, 0, 0, 0);
    e = __builtin_amdgcn_mfma_f32_16x16x32_bf16(qh, kl, e, 0, 0, 0);
    e = __builtin_amdgcn_mfma_f32_16x16x32_bf16(ql, kh, e, 0, 0, 0);
#pragma unroll
    for (int r = 0; r < 4; ++r)
      Ered[w * 256 + (lq * 4 + r) * 16 + l15] = e[r];
  }
  __syncthreads();

  if (tid < 256) {
    float e = Ered[tid] + Ered[256 + tid] + Ered[512 + tid] + Ered[768 + tid];
    partE[((size_t)(b * NCH_ + blockIdx.x)) * 256 + tid] = e;
  }
}

// ---------------------------------------------------------------------------
// k_softmax: reduce 576 partials and softmax over s. grid 4, block 256.
// ---------------------------------------------------------------------------
__global__ __launch_bounds__(256)
void k_softmax(const float* __restrict__ partE, float* __restrict__ heat) {
  const int b = blockIdx.x;
  const int tid = threadIdx.x;
  float e = 0.f;
  for (int ch = 0; ch < NCH_; ++ch)
    e += partE[((size_t)(b * NCH_ + ch)) * 256 + tid];
  float mx = e;
#pragma unroll
  for (int m = 1; m < 16; m <<= 1) mx = fmaxf(mx, __shfl_xor(mx, m, 64));
  float ex = expf(e - mx);
  float sm = ex;
#pragma unroll
  for (int m = 1; m < 16; m <<= 1) sm += __shfl_xor(sm, m, 64);
  heat[b * 256 + tid] = ex / sm;
}

// ---------------------------------------------------------------------------
// k_mix (MFMA, unchanged from round 8): out = gamma*(Wv@(heat@X)) + bias + res
// ---------------------------------------------------------------------------
__global__ __launch_bounds__(256, 3)
void k_mix(const float* __restrict__ x, const float* __restrict__ heat,
           const short* __restrict__ wvb, const float* __restrict__ bv,
           const float* __restrict__ gam, float* __restrict__ out) {
  __shared__ __attribute__((aligned(16))) short sm[20480];  // 40 KB union

  const int b    = blockIdx.y;
  const int hw0  = blockIdx.x * 16;
  const int tid  = threadIdx.x;
  const int lane = tid & 63;
  const int w    = tid >> 6;      // wave 0..3
  const int l15  = lane & 15;
  const int lq   = lane >> 4;     // quarter 0..3

  union U8 { s16x8 v; int i[4]; unsigned u[4]; };
  const f32x4 fz = {0.f, 0.f, 0.f, 0.f};

  // ---- A1 fragment first (needed by GEMM1; hides under staging loads) ----
  U8 ha; ha.i[0] = ha.i[1] = ha.i[2] = ha.i[3] = 0;
  if (lane < 32) {
    const float* hp = heat + b * 256 + l15 * 16 + lq * 8;
    float4 h0 = *(const float4*)hp;
    float4 h1 = *(const float4*)(hp + 4);
    ha.u[0] = pkbf(h0.x, h0.y); ha.u[1] = pkbf(h0.z, h0.w);
    ha.u[2] = pkbf(h1.x, h1.y); ha.u[3] = pkbf(h1.z, h1.w);
  }

  // ---- stage x tile -> bf16 xs: row (ci*16+g), stride 20 shorts,
  //      s-pairs packed as ints at int-index (P ^ (ci&7)) ------------------
  {
    const int ci = tid >> 2, q = tid & 3;
    const int sx = ci & 7;
    const float* xp = x + ((size_t)b * T_ * C_ + ci) * HW_ + hw0 + q * 4;
    short* r0 = &sm[(ci * 16 + q * 4) * 20];
#pragma unroll
    for (int P = 0; P < 8; ++P) {
      float4 v0 = *(const float4*)(xp + (size_t)(2 * P) * C_ * HW_);
      float4 v1 = *(const float4*)(xp + (size_t)(2 * P + 1) * C_ * HW_);
      const int ip = (P ^ sx) * 2;    // short offset, 4B-aligned
      *(unsigned*)&r0[ip]      = pkbf(v0.x, v1.x);
      *(unsigned*)&r0[20 + ip] = pkbf(v0.y, v1.y);
      *(unsigned*)&r0[40 + ip] = pkbf(v0.z, v1.z);
      *(unsigned*)&r0[60 + ip] = pkbf(v0.w, v1.w);
    }
  }

  // ---- a2 fragments (prepacked bf16), issued now, consumed after GEMM1 ---
  U8 a2[8];
#pragma unroll
  for (int fr = 0; fr < 8; ++fr)
    a2[fr].v = *(const s16x8*)&wvb[(fr * 64 + lane) * 8];

  // wave-local: my staging writes are the only rows my GEMM1 reads
  asm volatile("s_waitcnt lgkmcnt(0)" ::: "memory");

  // ---- GEMM1: 16 MFMAs, ci = w*16+i (own staged rows, no barrier) --------
  const int lq2 = lq & 1;   // lanes lq>=2 alias lq-2's B rows (A there is 0)
  f32x4 c1[16];
#pragma unroll
  for (int i = 0; i < 16; ++i) {
    const int ci = w * 16 + i;
    const short* row = &sm[(ci * 16 + l15) * 20];
    const int base = (lq2 * 4) ^ (i & 4);          // int index, even
    int2 D0 = *(const int2*)&row[2 * base];        // ints base, base+1
    int2 D1 = *(const int2*)&row[2 * base + 4];    // ints base+2, base+3
    U8 bx;
    const int t3 = i & 3;                          // compile-time per iter
    bx.i[0] = (t3 == 0) ? D0.x : (t3 == 1) ? D0.y : (t3 == 2) ? D1.x : D1.y;
    bx.i[1] = (t3 == 0) ? D0.y : (t3 == 1) ? D0.x : (t3 == 2) ? D1.y : D1.x;
    bx.i[2] = (t3 == 0) ? D1.x : (t3 == 1) ? D1.y : (t3 == 2) ? D0.x : D0.y;
    bx.i[3] = (t3 == 0) ? D1.y : (t3 == 1) ? D1.x : (t3 == 2) ? D0.y : D0.x;
    c1[i] = __builtin_amdgcn_mfma_f32_16x16x32_bf16(ha.v, bx.v, fz, 0, 0, 0);
  }
  __syncthreads();   // all staging complete -> rc may read any row

  // ---- residual from LDS (xs): rc[(ct*4+r)*2+h] = int holding bf16 pair
  unsigned rc[32];
#pragma unroll
  for (int ct = 0; ct < 4; ++ct)
#pragma unroll
    for (int r = 0; r < 4; ++r) {
      const int c = ct * 16 + lq * 4 + r;
      const short* row = &sm[(c * 16 + l15) * 20];
      const int base = 4 * ((w >> 1) ^ (lq & 1)) + 2 * ((w & 1) ^ (r >> 1));
      int2 D = *(const int2*)&row[2 * base];
      rc[(ct * 4 + r) * 2 + 0] = (r & 1) ? (unsigned)D.y : (unsigned)D.x;
      rc[(ct * 4 + r) * 2 + 1] = (r & 1) ? (unsigned)D.x : (unsigned)D.y;
    }
  __syncthreads();   // all xs reads done; sm becomes xh

  // ---- write xh -> LDS [n=t*16+g][ci] (stride 72), ci-pairs cvt_pk'd -----
#pragma unroll
  for (int r = 0; r < 4; ++r) {
    const int t = lq * 4 + r;
    short* dst = &sm[(t * 16 + l15) * 72 + w * 16];
    u32x4 p0, p1;
    p0[0] = pkbf(c1[0][r],  c1[1][r]);  p0[1] = pkbf(c1[2][r],  c1[3][r]);
    p0[2] = pkbf(c1[4][r],  c1[5][r]);  p0[3] = pkbf(c1[6][r],  c1[7][r]);
    p1[0] = pkbf(c1[8][r],  c1[9][r]);  p1[1] = pkbf(c1[10][r], c1[11][r]);
    p1[2] = pkbf(c1[12][r], c1[13][r]); p1[3] = pkbf(c1[14][r], c1[15][r]);
    *(u32x4*)dst       = p0;
    *(u32x4*)(dst + 8) = p1;
  }

  f32x4 bvr[4];
#pragma unroll
  for (int ct = 0; ct < 4; ++ct)
    bvr[ct] = *(const f32x4*)(bv + ct * 16 + lq * 4);
  const float gamma = gam[0];
  __syncthreads();   // xh visible

  // ---- GEMM2 + epilogue: this wave owns t = w*4 .. w*4+3 ------------------
#pragma unroll
  for (int ntq = 0; ntq < 4; ++ntq) {
    const int t = w * 4 + ntq;
    const short* xr0 = &sm[(t * 16 + l15) * 72];
    s16x8 b0 = *(const s16x8*)(xr0 + lq * 8);        // k = ci   0..31 slice
    s16x8 b1 = *(const s16x8*)(xr0 + 32 + lq * 8);   // k = ci  32..63 slice
    float* op = out + ((size_t)(b * T_ + t) * C_) * HW_ + hw0 + l15;
    const int half = ntq >> 1, odd = ntq & 1;
#pragma unroll
    for (int ct = 0; ct < 4; ++ct) {
      f32x4 acc = __builtin_amdgcn_mfma_f32_16x16x32_bf16(a2[ct * 2 + 0].v, b0, fz, 0, 0, 0);
      acc = __builtin_amdgcn_mfma_f32_16x16x32_bf16(a2[ct * 2 + 1].v, b1, acc, 0, 0, 0);
      const int cb = ct * 16 + lq * 4;
#pragma unroll
      for (int r = 0; r < 4; ++r) {
        const unsigned v = rc[(ct * 4 + r) * 2 + half];
        union { unsigned u; float f; } z;
        z.u = odd ? (v & 0xffff0000u) : (v << 16);
        op[(size_t)(cb + r) * HW_] = gamma * (acc[r] + bvr[ct][r]) + z.f;
      }
    }
  }
}

// ---------------------------------------------------------------------------
extern "C" void kernel_launch(void* const* d_in, const int* in_sizes, int n_in,
                              void* d_out, int out_size, void* d_ws, size_t ws_size,
                              hipStream_t stream) {
  const float* x   = (const float*)d_in[0];
  const float* wq  = (const float*)d_in[1];
  const float* bq  = (const float*)d_in[2];
  const float* wk  = (const float*)d_in[3];
  const float* bk  = (const float*)d_in[4];
  const float* wv  = (const float*)d_in[5];
  const float* bv  = (const float*)d_in[6];
  const float* gam = (const float*)d_in[7];
  float* out = (float*)d_out;

  short* wqkb  = (short*)d_ws;                        // 3072 bf16
  short* wvb   = wqkb + 3072;                         // 4096 bf16
  float* partE = (float*)(wvb + 4096 + 1024);         // pad to 16B; 4*576*256 f
  float* heat  = partE + (size_t)B_ * NCH_ * 256;     // 4*256 floats

  k_prep   <<<1, 256, 0, stream>>>(wq, wk, wv, wqkb, wvb);
  k_energy <<<dim3(NCH_, B_), 512, 0, stream>>>(x, wqkb, bq, bk, partE);
  k_softmax<<<dim3(B_),       256, 0, stream>>>(partE, heat);
  k_mix    <<<dim3(HW_ / 16, B_), 256, 0, stream>>>(x, heat, wvb, bv, gam, out);
}